// Round 10
// baseline (120.616 us; speedup 1.0000x reference)
//
#include <hip/hip_runtime.h>

#define CIN   128
#define HH    224
#define WW    224
#define COUT  256
#define HO    222
#define WO    222
#define HWSZ  (224 * 224)

typedef unsigned short u16;
typedef unsigned int   u32;
typedef __bf16  bf16x8 __attribute__((ext_vector_type(8)));
typedef float   f32x4  __attribute__((ext_vector_type(4)));

__device__ __forceinline__ u16 f2bf(float f) {
  union { float f; u32 u; } v; v.f = f;
  u32 u = v.u;
  return (u16)((u + 0x7FFFu + ((u >> 16) & 1u)) >> 16);  // RNE
}

// ---------------- w-pack only (xp eliminated — staging fused into conv) -----
// wp [mt(2)][kh(3)][ch(2)][kw(3)][mr(128)][jc'(8)][e(8)], granule jc' holds
// c-block jc'^(mr&7). 144 blocks x 256 threads = 36864 granules.
__global__ void prep_w(const float* __restrict__ w, u16* __restrict__ wp) {
  int u    = blockIdx.x * 256 + threadIdx.x;  // 0..36863 (16B granules)
  int jcp  = u & 7;
  int mr   = (u >> 3) & 127;
  int rest = u >> 10;                         // ((mt*3+kh)*2+ch)*3+kw
  int kw   = rest % 3;
  int q    = rest / 3;
  int ch   = q & 1;
  int r    = q >> 1;
  int kh   = r % 3;
  int mt   = r / 3;
  int oc   = mt * 128 + mr;
  int cb   = ch * 64 + (jcp ^ (mr & 7)) * 8;
  u16 o[8];
#pragma unroll
  for (int e = 0; e < 8; ++e)
    o[e] = f2bf(w[((size_t)(oc * CIN + cb + e) * 3 + kh) * 3 + kw]);
  uint4 v;
  v.x = (u32)o[0] | ((u32)o[1] << 16);
  v.y = (u32)o[2] | ((u32)o[3] << 16);
  v.z = (u32)o[4] | ((u32)o[5] << 16);
  v.w = (u32)o[6] | ((u32)o[7] << 16);
  *(uint4*)(&wp[(size_t)u * 8]) = v;
}

// ---------------- main: conv with FUSED x staging (no xp intermediate) ------
// R9 falsified the cross-XCD-L2 banding theory at the kernel boundary: ROCm's
// kernel-end L2 writeback/invalidate means conv's xp reads were ALWAYS L3/HBM
// (~500-900cy) regardless of producer placement (R6: FETCH 10.3MB ~= 80% of
// xp refetched). Fix: drop xp entirely; each block stages its B-tile straight
// from the READ-ONLY fp32 x (clean lines -> L2-cacheable per XCD, no dirty-
// line coherence hazard) and does the bf16 convert in-kernel. R6 counters
// (VALU 13.5%, Mfma 27.5%, all pipes <30%) show the idle capacity for it.
// Staging per round (64ch x 128 cols): lane=column, loop granule g: 8 dword
// loads (each wave-instr = 256B contiguous of one channel plane, coalesced),
// pack -> ds_write_b128 at granule jc=g^(cl&7) (8-phase, conflict-free) ->
// byte-identical LDS image to the old xp staging. T14 split: loads for s+1
// issue at round-s top; cvt+write after compute; one barrier per round.
// Tile M=128 x N=112, 4 waves split M, acc[2][7]; grid 888, XCD-banded.
__global__ __launch_bounds__(256, 2) void conv_mfma(const u16* __restrict__ wp,
                                                    const float* __restrict__ x,
                                                    float* __restrict__ out) {
  __shared__ u16 ldsB[2][8192];    // 2 x 16KB: 128 staged cols x 64 elems

  const int tid  = threadIdx.x;
  const int lane = tid & 63;
  const int wave = tid >> 6;
  const int quad = lane >> 4;
  const int lr   = lane & 15;
  const int cl   = tid & 127;      // staging column 0..127 (fixed per thread)
  const int ghi  = tid >> 7;       // staging granule parity

  const int bx  = blockIdx.x;
  const int xcd = bx & 7;
  const int u   = xcd * 111 + (bx >> 3);  // 0..887, XCD-banded
  const int oh  = u >> 2;                 // 0..221
  const int mt  = (u >> 1) & 1;
  const int nt  = u & 1;

  // staging source column, clamped in-bounds (dup col 223 feeds masked cols)
  int colg = nt * 112 + cl;
  if (colg > 223) colg = 223;

  f32x4 acc[2][7];
#pragma unroll
  for (int i = 0; i < 2; ++i)
#pragma unroll
    for (int j = 0; j < 7; ++j) acc[i][j] = {0.f, 0.f, 0.f, 0.f};

  int swA[2];
#pragma unroll
  for (int ks = 0; ks < 2; ++ks)
    swA[ks] = ((ks * 4 + quad) ^ (lr & 7)) << 3;

  float xs[4][8];                  // in-flight staging tile (32 VGPR, static idx)

  // STAGE_LOAD(s): 32 coalesced dword loads for round s (row oh+(s>>1), ch s&1)
  auto STAGE_LOAD = [&](int s) {
    const int row = oh + (s >> 1);
    const float* base = x + (size_t)((s & 1) * 64) * HWSZ + (size_t)row * WW + colg;
#pragma unroll
    for (int it = 0; it < 4; ++it) {
      const float* src = base + (size_t)((it * 2 + ghi) * 8) * HWSZ;
#pragma unroll
      for (int e = 0; e < 8; ++e)
        xs[it][e] = src[(size_t)e * HWSZ];
    }
  };
  // STAGE_WRITE: cvt+pack -> 4x ds_write_b128, granule-swizzled (conflict-free)
  auto STAGE_WRITE = [&](u16* buf) {
#pragma unroll
    for (int it = 0; it < 4; ++it) {
      const int g  = it * 2 + ghi;
      const int jc = g ^ (cl & 7);
      uint4 v;
      v.x = (u32)f2bf(xs[it][0]) | ((u32)f2bf(xs[it][1]) << 16);
      v.y = (u32)f2bf(xs[it][2]) | ((u32)f2bf(xs[it][3]) << 16);
      v.z = (u32)f2bf(xs[it][4]) | ((u32)f2bf(xs[it][5]) << 16);
      v.w = (u32)f2bf(xs[it][6]) | ((u32)f2bf(xs[it][7]) << 16);
      *(uint4*)(&buf[cl * 64 + jc * 8]) = v;
    }
  };

  // prologue: round 0 staged; round 1 loads in flight during round 0 compute
  STAGE_LOAD(0);
  STAGE_WRITE(&ldsB[0][0]);
  __syncthreads();
  STAGE_LOAD(1);

#pragma unroll 1
  for (int s = 0; s < 6; ++s) {
    const int cur = s & 1;
    const int ch  = s & 1;
    const int kh  = s >> 1;

    // per-lane A base: wp [mt][kh][ch][kw][mr(128)][jc'(8)][e(8)]
    const u16* Ab = wp + (size_t)((mt * 3 + kh) * 2 + ch) * 24576 +
                    wave * 2048 + lr * 64;
    const u16* Bb = &ldsB[cur][0];

#pragma unroll
    for (int kw = 0; kw < 3; ++kw) {
      const int bq  = (lr + kw) * 64;          // local col offset (j adds 16 cols)
      const int sw7 = (lr + kw) & 7;
#pragma unroll
      for (int ks = 0; ks < 2; ++ks) {
        const int swB = ((ks * 4 + quad) ^ sw7) << 3;
        bf16x8 af[2], bg[7];
#pragma unroll
        for (int i = 0; i < 2; ++i)
          af[i] = *reinterpret_cast<const bf16x8*>(Ab + kw * 8192 + i * 1024 + swA[ks]);
#pragma unroll
        for (int j = 0; j < 7; ++j)
          bg[j] = *reinterpret_cast<const bf16x8*>(Bb + bq + j * 1024 + swB);
#pragma unroll
        for (int i = 0; i < 2; ++i)
#pragma unroll
          for (int j = 0; j < 7; ++j)
            acc[i][j] = __builtin_amdgcn_mfma_f32_16x16x32_bf16(af[i], bg[j], acc[i][j], 0, 0, 0);
      }
    }

    if (s < 5) {
      // write round s+1's tile (loads issued a full round ago -> latency hidden;
      // target buffer's round s-1 readers cleared by the end-of-s-1 barrier)
      STAGE_WRITE(&ldsB[cur ^ 1][0]);
      if (s < 4) STAGE_LOAD(s + 2);   // xs regs free; lands during round s+1
    }
    __syncthreads();
  }

  // epilogue: C/D map col=lane&15, row=quad*4+reg (m89/m91); mask cols >= 222
  const int mb = mt * 128 + wave * 32;
#pragma unroll
  for (int i = 0; i < 2; ++i) {
#pragma unroll
    for (int j = 0; j < 7; ++j) {
      const int col = nt * 112 + j * 16 + lr;
      if (col < WO) {
        float* op = out + (size_t)(mb + i * 16 + quad * 4) * (HO * WO) +
                    (size_t)oh * WO + col;
#pragma unroll
        for (int r = 0; r < 4; ++r)
          op[(size_t)r * (HO * WO)] = acc[i][j][r];
      }
    }
  }
}

// ---------------- fallback (ws too small): naive fp32 direct conv ----------------
__global__ void conv_naive(const float* __restrict__ x, const float* __restrict__ w,
                           float* __restrict__ out) {
  int idx = blockIdx.x * 256 + threadIdx.x;
  if (idx >= COUT * HO * WO) return;
  int ow  = idx % WO;
  int tmp = idx / WO;
  int oh  = tmp % HO;
  int oc  = tmp / HO;
  float s = 0.f;
  for (int c = 0; c < CIN; ++c)
    for (int kh = 0; kh < 3; ++kh) {
      const float* xr = &x[(size_t)(c * HH + oh + kh) * WW + ow];
      const float* wr = &w[((size_t)(oc * CIN + c) * 3 + kh) * 3];
      s += xr[0] * wr[0] + xr[1] * wr[1] + xr[2] * wr[2];
    }
  out[idx] = s;
}

extern "C" void kernel_launch(void* const* d_in, const int* in_sizes, int n_in,
                              void* d_out, int out_size, void* d_ws, size_t ws_size,
                              hipStream_t stream) {
  const float* x    = (const float*)d_in[0];
  const float* kern = (const float*)d_in[1];
  float* out        = (float*)d_out;

  const size_t WP_BYTES = (size_t)36864 * 16;        // 589,824

  if (ws_size >= WP_BYTES) {
    u16* wp = (u16*)d_ws;
    hipLaunchKernelGGL(prep_w, dim3(144), dim3(256), 0, stream, kern, wp);
    hipLaunchKernelGGL(conv_mfma, dim3(888), dim3(256), 0, stream, wp, x, out);
  } else {
    int total = COUT * HO * WO;
    hipLaunchKernelGGL(conv_naive, dim3((total + 255) / 256), dim3(256), 0, stream,
                       x, kern, out);
  }
}

// Round 11
// 116.396 us; speedup vs baseline: 1.0363x; 1.0363x over previous
//
#include <hip/hip_runtime.h>

#define CIN   128
#define HH    224
#define WW    224
#define COUT  256
#define HO    222
#define WO    222
#define HWSZ  (224 * 224)
#define PLANE (224 * 224 * 64)   // one channel-half plane of packed x, in elems

typedef unsigned short u16;
typedef unsigned int   u32;
typedef __bf16  bf16x8 __attribute__((ext_vector_type(8)));
typedef float   f32x4  __attribute__((ext_vector_type(4)));

__device__ __forceinline__ u16 f2bf(float f) {
  union { float f; u32 u; } v; v.f = f;
  u32 u = v.u;
  return (u16)((u + 0x7FFFu + ((u >> 16) & 1u)) >> 16);  // RNE
}

// ---------------- pre-pass (round-5 proven version) ----------------
// blocks 0..447: pack x -> xp [ch(2)][h(224)][w(224)][jc'(8)][e(8)] bf16,
//   granule jc' holds c-block jc'^(w&7); write-side transpose tileT[w][c].
// blocks 448..591: pack w -> wp [mt(2)][kh(3)][ch(2)][kw(3)][mr(128)][jc'(8)][e(8)],
//   granule jc' holds c-block jc'^(mr&7).
__global__ void prep(const float* __restrict__ x, const float* __restrict__ w,
                     u16* __restrict__ xp, u16* __restrict__ wp) {
  const int t = threadIdx.x;
  if (blockIdx.x < 448) {
    const int h  = blockIdx.x >> 1;
    const int ch = blockIdx.x & 1;
    __shared__ u16 tileT[224][72];              // 32,256 B
#pragma unroll
    for (int i = 0; i < 14; ++i) {              // 64 c-rows * 56 float4
      int idx = i * 256 + t;
      int c   = idx / 56;
      int wq  = idx % 56;
      float4 v = *(const float4*)(&x[(size_t)(ch * 64 + c) * HWSZ + h * WW + wq * 4]);
      tileT[wq * 4 + 0][c] = f2bf(v.x);
      tileT[wq * 4 + 1][c] = f2bf(v.y);
      tileT[wq * 4 + 2][c] = f2bf(v.z);
      tileT[wq * 4 + 3][c] = f2bf(v.w);
    }
    __syncthreads();
#pragma unroll
    for (int i = 0; i < 7; ++i) {               // 224 w * 8 granules
      int idx  = i * 256 + t;
      int ww   = idx >> 3;
      int jcp  = idx & 7;
      int jsrc = (jcp ^ (ww & 7)) * 8;          // contiguous 8 u16 -> b128
      uint4 v = *(const uint4*)(&tileT[ww][jsrc]);
      *(uint4*)(&xp[(size_t)ch * PLANE + (size_t)(h * WW + ww) * 64 + jcp * 8]) = v;
    }
  } else {
    int u    = (blockIdx.x - 448) * 256 + t;    // 0..36863 (16B granules of wp)
    int jcp  = u & 7;
    int mr   = (u >> 3) & 127;
    int rest = u >> 10;                         // ((mt*3+kh)*2+ch)*3+kw
    int kw   = rest % 3;
    int q    = rest / 3;
    int ch   = q & 1;
    int r    = q >> 1;
    int kh   = r % 3;
    int mt   = r / 3;
    int oc   = mt * 128 + mr;
    int cb   = ch * 64 + (jcp ^ (mr & 7)) * 8;
    u16 o[8];
#pragma unroll
    for (int e = 0; e < 8; ++e)
      o[e] = f2bf(w[((size_t)(oc * CIN + cb + e) * 3 + kh) * 3 + kw]);
    uint4 v;
    v.x = (u32)o[0] | ((u32)o[1] << 16);
    v.y = (u32)o[2] | ((u32)o[3] << 16);
    v.z = (u32)o[4] | ((u32)o[5] << 16);
    v.w = (u32)o[6] | ((u32)o[7] << 16);
    *(uint4*)(&wp[(size_t)u * 8]) = v;
  }
}

// ---------------- async global->LDS, 16B per lane ----------------
__device__ __forceinline__ void lds_dma16(const u16* g, u16* l) {
  __builtin_amdgcn_global_load_lds(
      reinterpret_cast<__attribute__((address_space(1))) u32*>(
          reinterpret_cast<uintptr_t>(g)),
      reinterpret_cast<__attribute__((address_space(3))) u32*>(
          reinterpret_cast<uintptr_t>(l)),
      16, 0, 0);
}

#define VMCNT(n)  asm volatile("s_waitcnt vmcnt(" #n ")" ::: "memory")
#define SCHED0    __builtin_amdgcn_sched_barrier(0)
#define RAWBAR    __builtin_amdgcn_s_barrier()

// ---------------- main: T3+T4 counted-vmcnt 3-buffer pipeline ---------------
// All prior variants drained vmcnt->0 at every round barrier (syncthreads
// semantics) and/or forced in-order staging drains at every A-load wait.
// This kernel: 3 LDS buffers, staging issued 2 rounds ahead, A-frags reg-
// double-buffered 1 round ahead, compute has ZERO vmem waits, and each round
// ends with hand-counted s_waitcnt vmcnt(4) (STAGE(s+2) stays in flight
// across the raw s_barrier — never drains to 0; m218's lever).
// Per-wave vmem ledger (issue order pinned by sched_barrier(0) fences):
//   prologue: [STAGE(0):4][af(0):12][STAGE(1):4] -> vmcnt(4) -> bar
//   round s : issue [af(s+1):12][STAGE(s+2):4]; compute(s) from regs+LDS;
//             vmcnt(4) (drains STAGE(s+1)+af(s+1)) -> raw bar
//   round 4 : no STAGE -> vmcnt(0); round 5: compute only.
// WAR safe: STAGE(s+2) targets buf[(s+2)%3] whose readers (round s-1)
// finished before the previous barrier. Tile/epilogue identical to R5.
__global__ __launch_bounds__(256, 2) void conv_mfma(const u16* __restrict__ wp,
                                                    const u16* __restrict__ xp,
                                                    float* __restrict__ out) {
  __shared__ u16 ldsB[3][8192];    // 3 x 16KB: 128 staged cols x 64 elems

  const int tid  = threadIdx.x;
  const int lane = tid & 63;
  const int wave = tid >> 6;
  const int quad = lane >> 4;
  const int lr   = lane & 15;

  const int bx  = blockIdx.x;
  const int xcd = bx & 7;
  const int u   = xcd * 111 + (bx >> 3);  // 0..887, XCD-banded (888%8==0)
  const int oh  = u >> 2;                 // 0..221
  const int mt  = (u >> 1) & 1;
  const int nt  = u & 1;

  f32x4 acc[2][7];
#pragma unroll
  for (int i = 0; i < 2; ++i)
#pragma unroll
    for (int j = 0; j < 7; ++j) acc[i][j] = {0.f, 0.f, 0.f, 0.f};

  int swA[2];
#pragma unroll
  for (int ks = 0; ks < 2; ++ks)
    swA[ks] = ((ks * 4 + quad) ^ (lr & 7)) << 3;

  bf16x8 afA[3][2][2], afB[3][2][2];   // A-frag double buffer (2 x 48 VGPR)

#define LOAD_AF(AF, sn) do {                                                   \
    const u16* Ab_ = wp + (size_t)((mt * 3 + ((sn) >> 1)) * 2 + ((sn) & 1)) *  \
                     24576 + wave * 2048 + lr * 64;                            \
    _Pragma("unroll") for (int kw = 0; kw < 3; ++kw)                           \
    _Pragma("unroll") for (int ks = 0; ks < 2; ++ks)                           \
    _Pragma("unroll") for (int i = 0; i < 2; ++i)                              \
      AF[kw][ks][i] = *reinterpret_cast<const bf16x8*>(                        \
          Ab_ + kw * 8192 + i * 1024 + swA[ks]);                               \
  } while (0)

#define STAGE(sn) do {                                                         \
    const u16* g_ = xp + (size_t)((sn) & 1) * PLANE +                          \
                    (size_t)(oh + ((sn) >> 1)) * (WW * 64) + nt * (112 * 64);  \
    u16* d_ = &ldsB[(sn) % 3][0];                                              \
    _Pragma("unroll") for (int uu = 0; uu < 4; ++uu) {                         \
      const int unit_ = wave * 4 + uu;                                         \
      lds_dma16(g_ + unit_ * 512 + lane * 8, d_ + unit_ * 512);                \
    }                                                                          \
  } while (0)

#define COMPUTE(s, AF) do {                                                    \
    const u16* Bb_ = &ldsB[(s) % 3][0];                                        \
    _Pragma("unroll") for (int kw = 0; kw < 3; ++kw) {                         \
      const int bq_  = (lr + kw) * 64;                                         \
      const int sw7_ = (lr + kw) & 7;                                          \
      _Pragma("unroll") for (int ks = 0; ks < 2; ++ks) {                       \
        const int swB_ = ((ks * 4 + quad) ^ sw7_) << 3;                        \
        bf16x8 bg[7];                                                          \
        _Pragma("unroll") for (int j = 0; j < 7; ++j)                          \
          bg[j] = *reinterpret_cast<const bf16x8*>(Bb_ + bq_ + j * 1024 + swB_);\
        _Pragma("unroll") for (int i = 0; i < 2; ++i)                          \
        _Pragma("unroll") for (int j = 0; j < 7; ++j)                          \
          acc[i][j] = __builtin_amdgcn_mfma_f32_16x16x32_bf16(                 \
              AF[kw][ks][i], bg[j], acc[i][j], 0, 0, 0);                       \
      }                                                                        \
    }                                                                          \
  } while (0)

  // ---- prologue ----
  STAGE(0);          SCHED0;
  LOAD_AF(afA, 0);   SCHED0;
  STAGE(1);          SCHED0;
  VMCNT(4);          SCHED0;       // STAGE(0)+af(0) done; STAGE(1) in flight
  RAWBAR;            SCHED0;

  // ---- round 0 ----
  LOAD_AF(afB, 1);   SCHED0;
  STAGE(2);          SCHED0;
  COMPUTE(0, afA);
  VMCNT(4);          SCHED0;       // STAGE(1)+af(1) done; STAGE(2) in flight
  RAWBAR;            SCHED0;
  // ---- round 1 ----
  LOAD_AF(afA, 2);   SCHED0;
  STAGE(3);          SCHED0;
  COMPUTE(1, afB);
  VMCNT(4);          SCHED0;
  RAWBAR;            SCHED0;
  // ---- round 2 ----
  LOAD_AF(afB, 3);   SCHED0;
  STAGE(4);          SCHED0;
  COMPUTE(2, afA);
  VMCNT(4);          SCHED0;
  RAWBAR;            SCHED0;
  // ---- round 3 ----
  LOAD_AF(afA, 4);   SCHED0;
  STAGE(5);          SCHED0;
  COMPUTE(3, afB);
  VMCNT(4);          SCHED0;
  RAWBAR;            SCHED0;
  // ---- round 4 (no more staging) ----
  LOAD_AF(afB, 5);   SCHED0;
  COMPUTE(4, afA);
  VMCNT(0);          SCHED0;       // STAGE(5)+af(5) done
  RAWBAR;            SCHED0;
  // ---- round 5 ----
  COMPUTE(5, afB);

#undef LOAD_AF
#undef STAGE
#undef COMPUTE

  // epilogue: C/D map col=lane&15, row=quad*4+reg (m89/m91); mask cols >= 222
  const int mb = mt * 128 + wave * 32;
#pragma unroll
  for (int i = 0; i < 2; ++i) {
#pragma unroll
    for (int j = 0; j < 7; ++j) {
      const int col = nt * 112 + j * 16 + lr;
      if (col < WO) {
        float* op = out + (size_t)(mb + i * 16 + quad * 4) * (HO * WO) +
                    (size_t)oh * WO + col;
#pragma unroll
        for (int r = 0; r < 4; ++r)
          op[(size_t)r * (HO * WO)] = acc[i][j][r];
      }
    }
  }
}

// ---------------- fallback (ws too small): naive fp32 direct conv ----------------
__global__ void conv_naive(const float* __restrict__ x, const float* __restrict__ w,
                           float* __restrict__ out) {
  int idx = blockIdx.x * 256 + threadIdx.x;
  if (idx >= COUT * HO * WO) return;
  int ow  = idx % WO;
  int tmp = idx / WO;
  int oh  = tmp % HO;
  int oc  = tmp / HO;
  float s = 0.f;
  for (int c = 0; c < CIN; ++c)
    for (int kh = 0; kh < 3; ++kh) {
      const float* xr = &x[(size_t)(c * HH + oh + kh) * WW + ow];
      const float* wr = &w[((size_t)(oc * CIN + c) * 3 + kh) * 3];
      s += xr[0] * wr[0] + xr[1] * wr[1] + xr[2] * wr[2];
    }
  out[idx] = s;
}

extern "C" void kernel_launch(void* const* d_in, const int* in_sizes, int n_in,
                              void* d_out, int out_size, void* d_ws, size_t ws_size,
                              hipStream_t stream) {
  const float* x    = (const float*)d_in[0];
  const float* kern = (const float*)d_in[1];
  float* out        = (float*)d_out;

  const size_t WP_BYTES = (size_t)36864 * 16;        // 589,824
  const size_t XP_BYTES = (size_t)2 * PLANE * 2;     // 12,845,056

  if (ws_size >= WP_BYTES + XP_BYTES) {
    u16* wp = (u16*)d_ws;
    u16* xp = (u16*)((char*)d_ws + WP_BYTES);
    hipLaunchKernelGGL(prep, dim3(592), dim3(256), 0, stream, x, kern, xp, wp);
    hipLaunchKernelGGL(conv_mfma, dim3(888), dim3(256), 0, stream, wp, xp, out);
  } else {
    int total = COUT * HO * WO;
    hipLaunchKernelGGL(conv_naive, dim3((total + 255) / 256), dim3(256), 0, stream,
                       x, kern, out);
  }
}